// Round 1
// baseline (165.461 us; speedup 1.0000x reference)
//
#include <hip/hip_runtime.h>
#include <hip/hip_bf16.h>

// LIF: V = V + (I - V)/tau; spike = V >= 1.0; V = spike ? 0 : V
// Reference returns (spike_trace[T,B,N] as bool -> float 0/1, voltage_trace[T,B,N] f32),
// concatenated flat into d_out: [spikes | voltages].
//
// T sequential per neuron; B*N = 131072 neurons fully parallel.
// One thread per neuron, coalesced 4B accesses, stride B*N between timesteps.

#define LIF_T 512
#define V_TH 1.0f
#define TAU 20.0f

__global__ __launch_bounds__(256) void lif_kernel(const float* __restrict__ in,
                                                  float* __restrict__ spikes,
                                                  float* __restrict__ volts,
                                                  int BN) {
    const int i = blockIdx.x * blockDim.x + threadIdx.x;
    if (i >= BN) return;

    float V = 0.0f;
    size_t off = (size_t)i;

    #pragma unroll 4
    for (int t = 0; t < LIF_T; ++t, off += (size_t)BN) {
        const float I = in[off];
        // EXACT reference op order in f32: sub, IEEE div by 20.0f, add.
        V = V + (I - V) / TAU;
        const bool s = (V >= V_TH);
        spikes[off] = s ? 1.0f : 0.0f;
        V = s ? 0.0f : V;
        volts[off] = V;
    }
}

extern "C" void kernel_launch(void* const* d_in, const int* in_sizes, int n_in,
                              void* d_out, int out_size, void* d_ws, size_t ws_size,
                              hipStream_t stream) {
    const float* in = (const float*)d_in[0];
    float* out = (float*)d_out;

    const int total = in_sizes[0];          // T*B*N
    const int BN = total / LIF_T;           // 32*4096 = 131072

    float* spikes = out;                     // first T*B*N floats
    float* volts  = out + (size_t)total;     // second T*B*N floats

    const int block = 256;
    const int grid = (BN + block - 1) / block;   // 512 blocks
    lif_kernel<<<grid, block, 0, stream>>>(in, spikes, volts, BN);
}

// Round 2
// 146.230 us; speedup vs baseline: 1.1315x; 1.1315x over previous
//
#include <hip/hip_runtime.h>
#include <hip/hip_bf16.h>

// LIF: V = V + (I - V)/tau; spike = V >= 1.0; V = spike ? 0 : V
// d_out = [spike_trace (0/1 f32) | voltage_trace (f32)], each T*B*N.
//
// Memory-bound streaming kernel: 268 MB read + 537 MB write, zero reuse.
// - 1 thread per neuron (B*N = 131072), T=512 sequential inner loop.
// - Explicit 8-deep load batching: 8 independent HBM loads in flight per wave
//   before the loop-carried V chain consumes them (2 waves/SIMD only, so ILP
//   must cover the ~900cy HBM latency).
// - Nontemporal loads/stores: pure streaming, bypass L2/LLC allocation.

#define LIF_T 512
#define V_TH 1.0f
#define TAU 20.0f
#define UNROLL 8

__global__ __launch_bounds__(256) void lif_kernel(const float* __restrict__ in,
                                                  float* __restrict__ spikes,
                                                  float* __restrict__ volts,
                                                  int BN) {
    const int i = blockIdx.x * blockDim.x + threadIdx.x;
    if (i >= BN) return;

    float V = 0.0f;
    size_t off = (size_t)i;
    const size_t stride = (size_t)BN;

    for (int t = 0; t < LIF_T; t += UNROLL) {
        // Batch-issue UNROLL independent loads (addresses don't depend on V).
        float Iv[UNROLL];
        #pragma unroll
        for (int u = 0; u < UNROLL; ++u)
            Iv[u] = __builtin_nontemporal_load(&in[off + (size_t)u * stride]);

        // Loop-carried V chain + streaming stores.
        #pragma unroll
        for (int u = 0; u < UNROLL; ++u) {
            const size_t o = off + (size_t)u * stride;
            // EXACT reference op order in f32: sub, IEEE div by 20.0f, add.
            V = V + (Iv[u] - V) / TAU;
            const bool s = (V >= V_TH);
            __builtin_nontemporal_store(s ? 1.0f : 0.0f, &spikes[o]);
            V = s ? 0.0f : V;
            __builtin_nontemporal_store(V, &volts[o]);
        }
        off += (size_t)UNROLL * stride;
    }
}

extern "C" void kernel_launch(void* const* d_in, const int* in_sizes, int n_in,
                              void* d_out, int out_size, void* d_ws, size_t ws_size,
                              hipStream_t stream) {
    const float* in = (const float*)d_in[0];
    float* out = (float*)d_out;

    const int total = in_sizes[0];          // T*B*N
    const int BN = total / LIF_T;           // 32*4096 = 131072

    float* spikes = out;                     // first T*B*N floats
    float* volts  = out + (size_t)total;     // second T*B*N floats

    const int block = 256;
    const int grid = (BN + block - 1) / block;   // 512 blocks
    lif_kernel<<<grid, block, 0, stream>>>(in, spikes, volts, BN);
}